// Round 5
// baseline (685.084 us; speedup 1.0000x reference)
//
#include <hip/hip_runtime.h>
#include <hip/hip_bf16.h>
#include <cstdint>
#include <cstddef>

#define D 256

typedef __attribute__((ext_vector_type(8))) short bf16x8;
typedef __attribute__((ext_vector_type(4))) float f32x4;
typedef __attribute__((ext_vector_type(4))) unsigned short ushort4v;
typedef __attribute__((ext_vector_type(8))) unsigned short ushort8v;

__device__ __forceinline__ unsigned short f2bf(float f) {  // RNE
  union { float f; unsigned int u; } v; v.f = f;
  unsigned int u = v.u;
  u += ((u >> 16) & 1u) + 0x7fffu;
  return (unsigned short)(u >> 16);
}
__device__ __forceinline__ float bf2f(unsigned short s) {
  union { unsigned int u; float f; } v; v.u = ((unsigned int)s) << 16;
  return v.f;
}

#define GLL16(g, l) __builtin_amdgcn_global_load_lds( \
    (const __attribute__((address_space(1))) void*)(g), \
    (__attribute__((address_space(3))) void*)(l), 16, 0, 0)

// ---------------- CSR build ----------------

__global__ __launch_bounds__(256) void k_deg(const int* __restrict__ dst,
                                             int* __restrict__ deg, int E) {
  int e = blockIdx.x * 256 + threadIdx.x;
  if (e < E) atomicAdd(&deg[dst[e]], 1);
}

__global__ __launch_bounds__(256) void k_bsum(const int* __restrict__ deg,
                                              int* __restrict__ bsum, int M) {
  __shared__ int sm[256];
  int tid = threadIdx.x;
  int base = blockIdx.x * 1024 + tid * 4;
  int s = 0;
#pragma unroll
  for (int i = 0; i < 4; ++i) s += (base + i < M) ? deg[base + i] : 0;
  sm[tid] = s;
  __syncthreads();
  for (int off = 128; off > 0; off >>= 1) {
    if (tid < off) sm[tid] += sm[tid + off];
    __syncthreads();
  }
  if (tid == 0) bsum[blockIdx.x] = sm[0];
}

__global__ __launch_bounds__(64) void k_scanb(const int* __restrict__ bsum,
                                              int* __restrict__ boff,
                                              int* __restrict__ row_ptr,
                                              int nb, int M) {
  int l = threadIdx.x;
  int orig = (l < nb) ? bsum[l] : 0;
  int v = orig;
  for (int off = 1; off < 64; off <<= 1) {
    int t = __shfl_up(v, off);
    if (l >= off) v += t;
  }
  if (l < nb) boff[l] = v - orig;
  if (l == nb - 1) row_ptr[M] = v;
}

__global__ __launch_bounds__(256) void k_apply(const int* __restrict__ deg,
                                               const int* __restrict__ boff,
                                               int* __restrict__ row_ptr,
                                               int* __restrict__ cursor, int M) {
  __shared__ int sm[256];
  int tid = threadIdx.x;
  int base = blockIdx.x * 1024 + tid * 4;
  int d[4], p[4];
#pragma unroll
  for (int i = 0; i < 4; ++i) d[i] = (base + i < M) ? deg[base + i] : 0;
  p[0] = 0; p[1] = d[0]; p[2] = d[0] + d[1]; p[3] = d[0] + d[1] + d[2];
  int s = p[3] + d[3];
  sm[tid] = s;
  __syncthreads();
  for (int off = 1; off < 256; off <<= 1) {
    int t = (tid >= off) ? sm[tid - off] : 0;
    __syncthreads();
    sm[tid] += t;
    __syncthreads();
  }
  int excl = sm[tid] - s + boff[blockIdx.x];
#pragma unroll
  for (int i = 0; i < 4; ++i) {
    if (base + i < M) {
      row_ptr[base + i] = excl + p[i];
      cursor[base + i] = excl + p[i];
    }
  }
}

__global__ __launch_bounds__(256) void k_fill(const int* __restrict__ src,
                                              const int* __restrict__ dst,
                                              int* __restrict__ cursor,
                                              int* __restrict__ col, int E) {
  int e = blockIdx.x * 256 + threadIdx.x;
  if (e < E) {
    int p = atomicAdd(&cursor[dst[e]], 1);
    col[p] = src[e];
  }
}

// ---------------- fp32 -> split bf16 (hi, lo) ----------------

__global__ __launch_bounds__(256) void k_split(const float* __restrict__ in,
                                               unsigned short* __restrict__ oh,
                                               unsigned short* __restrict__ ol,
                                               int n4) {
  int i = blockIdx.x * 256 + threadIdx.x;
  if (i >= n4) return;
  float4 v = ((const float4*)in)[i];
  float a[4] = {v.x, v.y, v.z, v.w};
  ushort4v h, l;
#pragma unroll
  for (int j = 0; j < 4; ++j) {
    h[j] = f2bf(a[j]);
    l[j] = f2bf(a[j] - bf2f(h[j]));
  }
  ((ushort4v*)oh)[i] = h;
  ((ushort4v*)ol)[i] = l;
}

// all 5 weight matrices (each 256x256) in one dispatch; blockIdx.y selects.
__global__ __launch_bounds__(256) void k_splitw(
    const float* __restrict__ s0, const float* __restrict__ s1,
    const float* __restrict__ s2, const float* __restrict__ s3,
    const float* __restrict__ s4,
    unsigned short* __restrict__ h0, unsigned short* __restrict__ l0,
    unsigned short* __restrict__ h1, unsigned short* __restrict__ l1,
    unsigned short* __restrict__ h2, unsigned short* __restrict__ l2,
    unsigned short* __restrict__ h3, unsigned short* __restrict__ l3,
    unsigned short* __restrict__ h4, unsigned short* __restrict__ l4) {
  const float* s; unsigned short* oh; unsigned short* ol;
  switch (blockIdx.y) {
    case 0: s = s0; oh = h0; ol = l0; break;
    case 1: s = s1; oh = h1; ol = l1; break;
    case 2: s = s2; oh = h2; ol = l2; break;
    case 3: s = s3; oh = h3; ol = l3; break;
    default: s = s4; oh = h4; ol = l4; break;
  }
  int i = blockIdx.x * 256 + threadIdx.x;  // 16384 float4s per matrix
  float4 v = ((const float4*)s)[i];
  float a[4] = {v.x, v.y, v.z, v.w};
  ushort4v h, l;
#pragma unroll
  for (int j = 0; j < 4; ++j) {
    h[j] = f2bf(a[j]);
    l[j] = f2bf(a[j] - bf2f(h[j]));
  }
  ((ushort4v*)oh)[i] = h;
  ((ushort4v*)ol)[i] = l;
}

// ---------------- split-bf16 MFMA GEMM ----------------
// C[M, NBF+NF] = (Ah+Al)[M,256] @ (Wh+Wl)[NBF+NF,256]^T  (3-term split product)
// 1-D grid with bijective XCD-chunk swizzle, bx fastest (A-tile L2 reuse).
// bf16-out blocks (n0<NBF) use an LDS-staged epilogue for full-line stores.

__global__ __launch_bounds__(256) void k_gemm_mfma(
    const unsigned short* __restrict__ Ah, const unsigned short* __restrict__ Al,
    const unsigned short* __restrict__ Wh, const unsigned short* __restrict__ Wl,
    unsigned short* __restrict__ outBF, float* __restrict__ outF32,
    const float* __restrict__ bias, int M, int NBF, int NF, int relu,
    int nbxshift) {
  __shared__ char lds[36864];
  char* tA_h = lds;
  char* tA_l = lds + 8192;
  char* tW_h = lds + 16384;
  char* tW_l = lds + 24576;

  const int tid = threadIdx.x;
  const int wave = tid >> 6;
  const int lane = tid & 63;

  // bijective XCD-chunk swizzle: consecutive logical ids run on one XCD.
  int nwg = gridDim.x;
  int id = blockIdx.x;
  int q = nwg >> 3, r = nwg & 7;
  int xcd = id & 7, j = id >> 3;
  int w = ((xcd < r) ? xcd * (q + 1) : r * (q + 1) + (xcd - r) * q) + j;
  const int by = w >> nbxshift;
  const int bx = w & ((1 << nbxshift) - 1);
  const int n0 = bx * 128;

  // staging: linear LDS dest (base + lane*16), global source pre-permuted
  // so that a read at logical k-slot g uses physical slot g ^ ((row>>1)&3).
  int aoff[2], woff[2], ldso[2];
#pragma unroll
  for (int rr = 0; rr < 2; ++rr) {
    int o = rr * 4096 + wave * 1024 + lane * 16;  // byte offset in tile
    int row = o >> 6;                             // 64 B per row (32 bf16)
    int sp = (o >> 4) & 3;                        // physical 16B slot
    int sl = sp ^ ((row >> 1) & 3);               // logical k-slot stored here
    int arow = by * 128 + row; if (arow > M - 1) arow = M - 1;
    aoff[rr] = arow * 256 + sl * 8;               // elements
    woff[rr] = (n0 + row) * 256 + sl * 8;
    ldso[rr] = rr * 4096 + wave * 1024;           // wave-uniform LDS base
  }

  const int rbase = (wave >> 1) * 64;
  const int cbase = (wave & 1) * 64;
  const int fr = lane & 15;
  const int g = lane >> 4;

  int a_addr[4], w_addr[4];
#pragma unroll
  for (int m = 0; m < 4; ++m) {
    int row = rbase + m * 16 + fr;
    a_addr[m] = row * 64 + ((g ^ ((row >> 1) & 3)) * 16);
  }
#pragma unroll
  for (int n = 0; n < 4; ++n) {
    int row = cbase + n * 16 + fr;
    w_addr[n] = row * 64 + ((g ^ ((row >> 1) & 3)) * 16);
  }

  f32x4 acc[4][4] = {};

  for (int k0 = 0; k0 < 256; k0 += 32) {
    __syncthreads();
#pragma unroll
    for (int rr = 0; rr < 2; ++rr) {
      GLL16(Ah + aoff[rr] + k0, tA_h + ldso[rr]);
      GLL16(Al + aoff[rr] + k0, tA_l + ldso[rr]);
      GLL16(Wh + woff[rr] + k0, tW_h + ldso[rr]);
      GLL16(Wl + woff[rr] + k0, tW_l + ldso[rr]);
    }
    __syncthreads();
    bf16x8 ah[4], al[4], wh[4], wl[4];
#pragma unroll
    for (int m = 0; m < 4; ++m) {
      ah[m] = *(const bf16x8*)(tA_h + a_addr[m]);
      al[m] = *(const bf16x8*)(tA_l + a_addr[m]);
    }
#pragma unroll
    for (int n = 0; n < 4; ++n) {
      wh[n] = *(const bf16x8*)(tW_h + w_addr[n]);
      wl[n] = *(const bf16x8*)(tW_l + w_addr[n]);
    }
#pragma unroll
    for (int m = 0; m < 4; ++m)
#pragma unroll
      for (int n = 0; n < 4; ++n) {
        acc[m][n] = __builtin_amdgcn_mfma_f32_16x16x32_bf16(ah[m], wh[n], acc[m][n], 0, 0, 0);
        acc[m][n] = __builtin_amdgcn_mfma_f32_16x16x32_bf16(ah[m], wl[n], acc[m][n], 0, 0, 0);
        acc[m][n] = __builtin_amdgcn_mfma_f32_16x16x32_bf16(al[m], wh[n], acc[m][n], 0, 0, 0);
      }
  }

  // C/D layout: col = lane&15 (fr), row = g*4 + reg
  if (n0 < NBF) {
    // ---- bf16 output block: LDS-staged epilogue for full-line stores ----
    __syncthreads();  // all waves done reading the operand tiles
    char* wbuf = lds + wave * 9216;  // 64 rows x 144 B (64 cols bf16, padded)
#pragma unroll
    for (int n = 0; n < 4; ++n)
#pragma unroll
      for (int m = 0; m < 4; ++m) {
        f32x4 a = acc[m][n];
#pragma unroll
        for (int rr = 0; rr < 4; ++rr) {
          int row_l = m * 16 + g * 4 + rr;
          unsigned short self = f2bf(a[rr]);
          unsigned short part = f2bf(__shfl_xor(a[rr], 1));
          if ((fr & 1) == 0) {
            unsigned int pk = (unsigned int)self | ((unsigned int)part << 16);
            *(unsigned int*)(wbuf + row_l * 144 + (n * 16 + fr) * 2) = pk;
          }
        }
      }
    __builtin_amdgcn_s_waitcnt(0);  // lgkmcnt(0): wave-private region, no barrier needed
#pragma unroll
    for (int p = 0; p < 8; ++p) {
      int row_l = (lane >> 3) + p * 8;
      int row = by * 128 + rbase + row_l;
      ushort8v v = *(const ushort8v*)(wbuf + row_l * 144 + (lane & 7) * 16);
      if (row < M)
        *(ushort8v*)(outBF + (size_t)row * NBF + n0 + cbase + (lane & 7) * 8) = v;
    }
  } else {
    // ---- f32 output block: direct stores (already full-line) ----
#pragma unroll
    for (int n = 0; n < 4; ++n) {
      int col = n0 + cbase + n * 16 + fr;
      int fcol = col - NBF;
      float bv = bias ? bias[fcol] : 0.f;
#pragma unroll
      for (int m = 0; m < 4; ++m) {
        f32x4 a = acc[m][n];
#pragma unroll
        for (int rr = 0; rr < 4; ++rr) {
          int row = by * 128 + rbase + m * 16 + g * 4 + rr;
          if (row < M) {
            float v = a[rr] + bv;
            if (relu) v = fmaxf(v, 0.f);
            outF32[(size_t)row * NF + fcol] = v;
          }
        }
      }
    }
  }
}

// ---------------- aggregation ----------------
// one wave per node, 2 edges per iteration (16B loads); combine via shfl_xor(32).

__global__ __launch_bounds__(256) void k_agg2(const unsigned short* __restrict__ T1,
                                              const float* __restrict__ T2,
                                              unsigned short* __restrict__ Hh,
                                              unsigned short* __restrict__ Hl,
                                              const int* __restrict__ row_ptr,
                                              const int* __restrict__ col, int M) {
  int wave = threadIdx.x >> 6, lane = threadIdx.x & 63;
  int n = blockIdx.x * 4 + wave;
  if (n >= M) return;
  int beg = row_ptr[n], end = row_ptr[n + 1];
  int half = lane >> 5, sl = lane & 31;
  float s[8] = {0.f, 0.f, 0.f, 0.f, 0.f, 0.f, 0.f, 0.f};
  for (int j = beg + half; j < end; j += 2) {
    int srcr = col[j];
    ushort8v v = *(const ushort8v*)(T1 + (size_t)srcr * 256 + sl * 8);
#pragma unroll
    for (int i = 0; i < 8; ++i) s[i] += bf2f(v[i]);
  }
#pragma unroll
  for (int i = 0; i < 8; ++i) s[i] += __shfl_xor(s[i], 32);
  int dg = end - beg;
  float inv = 1.0f / (float)(dg > 0 ? dg : 1);
  const float4* t2p = (const float4*)(T2 + (size_t)n * 256 + sl * 8);
  float4 ta = t2p[0], tb = t2p[1];
  float h[8];
  h[0] = fmaxf(s[0] * inv + ta.x, 0.f);
  h[1] = fmaxf(s[1] * inv + ta.y, 0.f);
  h[2] = fmaxf(s[2] * inv + ta.z, 0.f);
  h[3] = fmaxf(s[3] * inv + ta.w, 0.f);
  h[4] = fmaxf(s[4] * inv + tb.x, 0.f);
  h[5] = fmaxf(s[5] * inv + tb.y, 0.f);
  h[6] = fmaxf(s[6] * inv + tb.z, 0.f);
  h[7] = fmaxf(s[7] * inv + tb.w, 0.f);
  if (half == 0) {
    ushort8v hh;
#pragma unroll
    for (int i = 0; i < 8; ++i) hh[i] = f2bf(h[i]);
    *(ushort8v*)(Hh + (size_t)n * 256 + sl * 8) = hh;
  } else {
    ushort8v hl;
#pragma unroll
    for (int i = 0; i < 8; ++i) {
      unsigned short hi = f2bf(h[i]);
      hl[i] = f2bf(h[i] - bf2f(hi));
    }
    *(ushort8v*)(Hl + (size_t)n * 256 + sl * 8) = hl;
  }
}

// ---------------- final: out = softmax(H[M,256] @ Wm2[8,256]^T + bm2) ----------------

__global__ __launch_bounds__(256) void k_final(const float* __restrict__ H,
                                               const float* __restrict__ Wm2,
                                               const float* __restrict__ bm2,
                                               float* __restrict__ out, int M) {
  int node = blockIdx.x * 4 + (threadIdx.x >> 6);
  int lane = threadIdx.x & 63;
  if (node >= M) return;
  int o = lane >> 3;
  int r = lane & 7;
  const float* h = H + (size_t)node * D;
  const float* w = Wm2 + (size_t)o * D;
  float p = 0.f;
  for (int k = r; k < D; k += 8) p += h[k] * w[k];
  p += __shfl_xor(p, 1);
  p += __shfl_xor(p, 2);
  p += __shfl_xor(p, 4);
  float logit = p + bm2[o];
  float m = logit;
  m = fmaxf(m, __shfl_xor(m, 8));
  m = fmaxf(m, __shfl_xor(m, 16));
  m = fmaxf(m, __shfl_xor(m, 32));
  float e = expf(logit - m);
  float s = e;
  s += __shfl_xor(s, 8);
  s += __shfl_xor(s, 16);
  s += __shfl_xor(s, 32);
  if (r == 0) out[(size_t)node * 8 + o] = e / s;
}

// ---------------- launch ----------------

extern "C" void kernel_launch(void* const* d_in, const int* in_sizes, int n_in,
                              void* d_out, int out_size, void* d_ws, size_t ws_size,
                              hipStream_t stream) {
  const float* x   = (const float*)d_in[0];
  const int*   ei  = (const int*)d_in[1];
  const float* W1l = (const float*)d_in[2];
  const float* b1  = (const float*)d_in[3];
  const float* W1r = (const float*)d_in[4];
  const float* W2l = (const float*)d_in[5];
  const float* b2  = (const float*)d_in[6];
  const float* W2r = (const float*)d_in[7];
  const float* Wm1 = (const float*)d_in[8];
  const float* bm1 = (const float*)d_in[9];
  const float* Wm2 = (const float*)d_in[10];
  const float* bm2 = (const float*)d_in[11];
  float* out = (float*)d_out;

  int M = in_sizes[0] / D;   // 50000
  int E = in_sizes[1] / 2;   // 800000
  const int* src = ei;
  const int* dst = ei + E;

  char* p = (char*)d_ws;
  auto alloc = [&](size_t bytes) {
    char* q = p;
    p += (bytes + 255) & ~(size_t)255;
    return q;
  };
  unsigned short* bh0  = (unsigned short*)alloc((size_t)M * 256 * 2);  // x/h split hi
  unsigned short* bh1  = (unsigned short*)alloc((size_t)M * 256 * 2);  // x/h split lo
  unsigned short* T1bf = (unsigned short*)alloc((size_t)M * 256 * 2);  // neighbor-path (bf16)
  float*          T2f  = (float*)alloc((size_t)M * 256 * 4);           // root-path / mlp out (f32)
  unsigned short* Wc1h = (unsigned short*)alloc(512 * 256 * 2);
  unsigned short* Wc1l = (unsigned short*)alloc(512 * 256 * 2);
  unsigned short* Wc2h = (unsigned short*)alloc(512 * 256 * 2);
  unsigned short* Wc2l = (unsigned short*)alloc(512 * 256 * 2);
  unsigned short* Wm1h = (unsigned short*)alloc(256 * 256 * 2);
  unsigned short* Wm1l = (unsigned short*)alloc(256 * 256 * 2);
  int* deg     = (int*)alloc((size_t)M * 4);
  int* row_ptr = (int*)alloc((size_t)(M + 1) * 4);
  int* cursor  = (int*)alloc((size_t)M * 4);
  int* col     = (int*)alloc((size_t)E * 4);
  int* bsum    = (int*)alloc(64 * 4);
  int* boff    = (int*)alloc(64 * 4);

  int nb = (M + 1023) / 1024;  // 49

  // CSR build
  hipMemsetAsync(deg, 0, (size_t)M * sizeof(int), stream);
  k_deg<<<dim3((E + 255) / 256), dim3(256), 0, stream>>>(dst, deg, E);
  k_bsum<<<dim3(nb), dim3(256), 0, stream>>>(deg, bsum, M);
  k_scanb<<<dim3(1), dim3(64), 0, stream>>>(bsum, boff, row_ptr, nb, M);
  k_apply<<<dim3(nb), dim3(256), 0, stream>>>(deg, boff, row_ptr, cursor, M);
  k_fill<<<dim3((E + 255) / 256), dim3(256), 0, stream>>>(src, dst, cursor, col, E);

  // split conversions
  int nx4 = M * 256 / 4;
  k_split<<<dim3((nx4 + 255) / 256), dim3(256), 0, stream>>>(x, bh0, bh1, nx4);
  k_splitw<<<dim3(64, 5), dim3(256), 0, stream>>>(
      W1l, W1r, W2l, W2r, Wm1,
      Wc1h, Wc1l, Wc1h + 65536, Wc1l + 65536,
      Wc2h, Wc2l, Wc2h + 65536, Wc2l + 65536,
      Wm1h, Wm1l);

  dim3 blk(256);
  int nwg4 = ((M + 127) / 128) * 4;  // 1564
  int nwg2 = ((M + 127) / 128) * 2;  // 782
  int aggGrid = (M + 3) / 4;

  // Layer 1: [T1 | T2] = x @ [W1l;W1r]^T ; T2 += b1 ; h1 = relu(mean(T1)+T2) -> split into bh0/bh1
  k_gemm_mfma<<<dim3(nwg4), blk, 0, stream>>>(bh0, bh1, Wc1h, Wc1l, T1bf, T2f, b1, M, 256, 256, 0, 2);
  k_agg2<<<dim3(aggGrid), blk, 0, stream>>>(T1bf, T2f, bh0, bh1, row_ptr, col, M);
  // Layer 2
  k_gemm_mfma<<<dim3(nwg4), blk, 0, stream>>>(bh0, bh1, Wc2h, Wc2l, T1bf, T2f, b2, M, 256, 256, 0, 2);
  k_agg2<<<dim3(aggGrid), blk, 0, stream>>>(T1bf, T2f, bh0, bh1, row_ptr, col, M);
  // MLP layer 1: h3 = relu(h2 @ Wm1^T + bm1) -> T2f
  k_gemm_mfma<<<dim3(nwg2), blk, 0, stream>>>(bh0, bh1, Wm1h, Wm1l, nullptr, T2f, bm1, M, 0, 256, 1, 1);
  // logits + softmax
  k_final<<<dim3((M + 3) / 4), blk, 0, stream>>>(T2f, Wm2, bm2, out, M);
}

// Round 6
// 580.448 us; speedup vs baseline: 1.1803x; 1.1803x over previous
//
#include <hip/hip_runtime.h>
#include <hip/hip_bf16.h>
#include <cstdint>
#include <cstddef>

#define D 256

typedef __attribute__((ext_vector_type(8))) short bf16x8;
typedef __attribute__((ext_vector_type(4))) float f32x4;
typedef __attribute__((ext_vector_type(4))) unsigned short ushort4v;
typedef __attribute__((ext_vector_type(8))) unsigned short ushort8v;

__device__ __forceinline__ unsigned short f2bf(float f) {  // RNE
  union { float f; unsigned int u; } v; v.f = f;
  unsigned int u = v.u;
  u += ((u >> 16) & 1u) + 0x7fffu;
  return (unsigned short)(u >> 16);
}
__device__ __forceinline__ float bf2f(unsigned short s) {
  union { unsigned int u; float f; } v; v.u = ((unsigned int)s) << 16;
  return v.f;
}

#define GLL16(g, l) __builtin_amdgcn_global_load_lds( \
    (const __attribute__((address_space(1))) void*)(g), \
    (__attribute__((address_space(3))) void*)(l), 16, 0, 0)

// ---------------- CSR build ----------------

__global__ __launch_bounds__(256) void k_deg(const int* __restrict__ dst,
                                             int* __restrict__ deg, int E) {
  int e = blockIdx.x * 256 + threadIdx.x;
  if (e < E) atomicAdd(&deg[dst[e]], 1);
}

__global__ __launch_bounds__(256) void k_bsum(const int* __restrict__ deg,
                                              int* __restrict__ bsum, int M) {
  __shared__ int sm[256];
  int tid = threadIdx.x;
  int base = blockIdx.x * 1024 + tid * 4;
  int s = 0;
#pragma unroll
  for (int i = 0; i < 4; ++i) s += (base + i < M) ? deg[base + i] : 0;
  sm[tid] = s;
  __syncthreads();
  for (int off = 128; off > 0; off >>= 1) {
    if (tid < off) sm[tid] += sm[tid + off];
    __syncthreads();
  }
  if (tid == 0) bsum[blockIdx.x] = sm[0];
}

__global__ __launch_bounds__(64) void k_scanb(const int* __restrict__ bsum,
                                              int* __restrict__ boff,
                                              int* __restrict__ row_ptr,
                                              int nb, int M) {
  int l = threadIdx.x;
  int orig = (l < nb) ? bsum[l] : 0;
  int v = orig;
  for (int off = 1; off < 64; off <<= 1) {
    int t = __shfl_up(v, off);
    if (l >= off) v += t;
  }
  if (l < nb) boff[l] = v - orig;
  if (l == nb - 1) row_ptr[M] = v;
}

__global__ __launch_bounds__(256) void k_apply(const int* __restrict__ deg,
                                               const int* __restrict__ boff,
                                               int* __restrict__ row_ptr,
                                               int* __restrict__ cursor, int M) {
  __shared__ int sm[256];
  int tid = threadIdx.x;
  int base = blockIdx.x * 1024 + tid * 4;
  int d[4], p[4];
#pragma unroll
  for (int i = 0; i < 4; ++i) d[i] = (base + i < M) ? deg[base + i] : 0;
  p[0] = 0; p[1] = d[0]; p[2] = d[0] + d[1]; p[3] = d[0] + d[1] + d[2];
  int s = p[3] + d[3];
  sm[tid] = s;
  __syncthreads();
  for (int off = 1; off < 256; off <<= 1) {
    int t = (tid >= off) ? sm[tid - off] : 0;
    __syncthreads();
    sm[tid] += t;
    __syncthreads();
  }
  int excl = sm[tid] - s + boff[blockIdx.x];
#pragma unroll
  for (int i = 0; i < 4; ++i) {
    if (base + i < M) {
      row_ptr[base + i] = excl + p[i];
      cursor[base + i] = excl + p[i];
    }
  }
}

__global__ __launch_bounds__(256) void k_fill(const int* __restrict__ src,
                                              const int* __restrict__ dst,
                                              int* __restrict__ cursor,
                                              int* __restrict__ col, int E) {
  int e = blockIdx.x * 256 + threadIdx.x;
  if (e < E) {
    int p = atomicAdd(&cursor[dst[e]], 1);
    col[p] = src[e];
  }
}

// ---------------- fp32 -> split bf16 (hi, lo) ----------------

__global__ __launch_bounds__(256) void k_split(const float* __restrict__ in,
                                               unsigned short* __restrict__ oh,
                                               unsigned short* __restrict__ ol,
                                               int n4) {
  int i = blockIdx.x * 256 + threadIdx.x;
  if (i >= n4) return;
  float4 v = ((const float4*)in)[i];
  float a[4] = {v.x, v.y, v.z, v.w};
  ushort4v h, l;
#pragma unroll
  for (int j = 0; j < 4; ++j) {
    h[j] = f2bf(a[j]);
    l[j] = f2bf(a[j] - bf2f(h[j]));
  }
  ((ushort4v*)oh)[i] = h;
  ((ushort4v*)ol)[i] = l;
}

// all 5 weight matrices (each 256x256) in one dispatch; blockIdx.y selects.
__global__ __launch_bounds__(256) void k_splitw(
    const float* __restrict__ s0, const float* __restrict__ s1,
    const float* __restrict__ s2, const float* __restrict__ s3,
    const float* __restrict__ s4,
    unsigned short* __restrict__ h0, unsigned short* __restrict__ l0,
    unsigned short* __restrict__ h1, unsigned short* __restrict__ l1,
    unsigned short* __restrict__ h2, unsigned short* __restrict__ l2,
    unsigned short* __restrict__ h3, unsigned short* __restrict__ l3,
    unsigned short* __restrict__ h4, unsigned short* __restrict__ l4) {
  const float* s; unsigned short* oh; unsigned short* ol;
  switch (blockIdx.y) {
    case 0: s = s0; oh = h0; ol = l0; break;
    case 1: s = s1; oh = h1; ol = l1; break;
    case 2: s = s2; oh = h2; ol = l2; break;
    case 3: s = s3; oh = h3; ol = l3; break;
    default: s = s4; oh = h4; ol = l4; break;
  }
  int i = blockIdx.x * 256 + threadIdx.x;  // 16384 float4s per matrix
  float4 v = ((const float4*)s)[i];
  float a[4] = {v.x, v.y, v.z, v.w};
  ushort4v h, l;
#pragma unroll
  for (int j = 0; j < 4; ++j) {
    h[j] = f2bf(a[j]);
    l[j] = f2bf(a[j] - bf2f(h[j]));
  }
  ((ushort4v*)oh)[i] = h;
  ((ushort4v*)ol)[i] = l;
}

// ---------------- split-bf16 MFMA GEMM ----------------
// C[M, NBF+NF] = (Ah+Al)[M,256] @ (Wh+Wl)[NBF+NF,256]^T  (3-term split product)
// 1-D grid, bijective XCD-chunk swizzle with bx fastest (A-tile L2 reuse).
// Pipelined K-loop (single LDS buffer): per step, frags -> regs, barrier,
// issue next step's global_load_lds, then MFMA while loads fly.

__global__ __launch_bounds__(256) void k_gemm_mfma(
    const unsigned short* __restrict__ Ah, const unsigned short* __restrict__ Al,
    const unsigned short* __restrict__ Wh, const unsigned short* __restrict__ Wl,
    unsigned short* __restrict__ outBF, float* __restrict__ outF32,
    const float* __restrict__ bias, int M, int NBF, int NF, int relu,
    int nbxshift) {
  __shared__ char lds[32768];
  char* tA_h = lds;
  char* tA_l = lds + 8192;
  char* tW_h = lds + 16384;
  char* tW_l = lds + 24576;

  const int tid = threadIdx.x;
  const int wave = tid >> 6;
  const int lane = tid & 63;

  // bijective XCD-chunk swizzle: consecutive logical ids run on one XCD.
  int nwg = gridDim.x;
  int id = blockIdx.x;
  int q = nwg >> 3, r = nwg & 7;
  int xcd = id & 7, j = id >> 3;
  int w = ((xcd < r) ? xcd * (q + 1) : r * (q + 1) + (xcd - r) * q) + j;
  const int by = w >> nbxshift;
  const int bx = w & ((1 << nbxshift) - 1);
  const int n0 = bx * 128;

  // staging: linear LDS dest (base + lane*16), global source pre-permuted
  // so that a read at logical k-slot g uses physical slot g ^ ((row>>1)&3).
  int aoff[2], woff[2], ldso[2];
#pragma unroll
  for (int rr = 0; rr < 2; ++rr) {
    int o = rr * 4096 + wave * 1024 + lane * 16;  // byte offset in tile
    int row = o >> 6;                             // 64 B per row (32 bf16)
    int sp = (o >> 4) & 3;                        // physical 16B slot
    int sl = sp ^ ((row >> 1) & 3);               // logical k-slot stored here
    int arow = by * 128 + row; if (arow > M - 1) arow = M - 1;
    aoff[rr] = arow * 256 + sl * 8;               // elements
    woff[rr] = (n0 + row) * 256 + sl * 8;
    ldso[rr] = rr * 4096 + wave * 1024;           // wave-uniform LDS base
  }

  const int rbase = (wave >> 1) * 64;
  const int cbase = (wave & 1) * 64;
  const int fr = lane & 15;
  const int g = lane >> 4;

  int a_addr[4], w_addr[4];
#pragma unroll
  for (int m = 0; m < 4; ++m) {
    int row = rbase + m * 16 + fr;
    a_addr[m] = row * 64 + ((g ^ ((row >> 1) & 3)) * 16);
  }
#pragma unroll
  for (int n = 0; n < 4; ++n) {
    int row = cbase + n * 16 + fr;
    w_addr[n] = row * 64 + ((g ^ ((row >> 1) & 3)) * 16);
  }

  f32x4 acc[4][4] = {};

  // prologue: stage k0 = 0
#pragma unroll
  for (int rr = 0; rr < 2; ++rr) {
    GLL16(Ah + aoff[rr], tA_h + ldso[rr]);
    GLL16(Al + aoff[rr], tA_l + ldso[rr]);
    GLL16(Wh + woff[rr], tW_h + ldso[rr]);
    GLL16(Wl + woff[rr], tW_l + ldso[rr]);
  }

  for (int k0 = 0; k0 < 256; k0 += 32) {
    __syncthreads();  // implicit vmcnt(0): staged tile ready for all waves
    bf16x8 ah[4], al[4], wh[4], wl[4];
#pragma unroll
    for (int m = 0; m < 4; ++m) {
      ah[m] = *(const bf16x8*)(tA_h + a_addr[m]);
      al[m] = *(const bf16x8*)(tA_l + a_addr[m]);
    }
#pragma unroll
    for (int n = 0; n < 4; ++n) {
      wh[n] = *(const bf16x8*)(tW_h + w_addr[n]);
      wl[n] = *(const bf16x8*)(tW_l + w_addr[n]);
    }
    __syncthreads();  // implicit lgkmcnt(0): all waves' frags in regs, LDS dead
    if (k0 < 224) {   // stage k0+32 while MFMAs run (wave-uniform branch)
      int ko = k0 + 32;
#pragma unroll
      for (int rr = 0; rr < 2; ++rr) {
        GLL16(Ah + aoff[rr] + ko, tA_h + ldso[rr]);
        GLL16(Al + aoff[rr] + ko, tA_l + ldso[rr]);
        GLL16(Wh + woff[rr] + ko, tW_h + ldso[rr]);
        GLL16(Wl + woff[rr] + ko, tW_l + ldso[rr]);
      }
    }
#pragma unroll
    for (int m = 0; m < 4; ++m)
#pragma unroll
      for (int n = 0; n < 4; ++n) {
        acc[m][n] = __builtin_amdgcn_mfma_f32_16x16x32_bf16(ah[m], wh[n], acc[m][n], 0, 0, 0);
        acc[m][n] = __builtin_amdgcn_mfma_f32_16x16x32_bf16(ah[m], wl[n], acc[m][n], 0, 0, 0);
        acc[m][n] = __builtin_amdgcn_mfma_f32_16x16x32_bf16(al[m], wh[n], acc[m][n], 0, 0, 0);
      }
  }

  // epilogue: C/D layout col=lane&15, row=(lane>>4)*4+reg — direct stores
#pragma unroll
  for (int n = 0; n < 4; ++n) {
    int col = n0 + cbase + n * 16 + fr;
    bool isbf = col < NBF;
    int fcol = col - NBF;
    float bv = (!isbf && bias) ? bias[fcol] : 0.f;
#pragma unroll
    for (int m = 0; m < 4; ++m) {
      f32x4 a = acc[m][n];
#pragma unroll
      for (int rr = 0; rr < 4; ++rr) {
        int row = by * 128 + rbase + m * 16 + g * 4 + rr;
        if (row < M) {
          if (isbf) {
            outBF[(size_t)row * NBF + col] = f2bf(a[rr]);
          } else {
            float v = a[rr] + bv;
            if (relu) v = fmaxf(v, 0.f);
            outF32[(size_t)row * NF + fcol] = v;
          }
        }
      }
    }
  }
}

// ---------------- aggregation ----------------
// one wave per node, 2 edges per iteration (16B loads); combine via shfl_xor(32).

__global__ __launch_bounds__(256) void k_agg2(const unsigned short* __restrict__ T1,
                                              const float* __restrict__ T2,
                                              unsigned short* __restrict__ Hh,
                                              unsigned short* __restrict__ Hl,
                                              const int* __restrict__ row_ptr,
                                              const int* __restrict__ col, int M) {
  int wave = threadIdx.x >> 6, lane = threadIdx.x & 63;
  int n = blockIdx.x * 4 + wave;
  if (n >= M) return;
  int beg = row_ptr[n], end = row_ptr[n + 1];
  int half = lane >> 5, sl = lane & 31;
  float s[8] = {0.f, 0.f, 0.f, 0.f, 0.f, 0.f, 0.f, 0.f};
  for (int j = beg + half; j < end; j += 2) {
    int srcr = col[j];
    ushort8v v = *(const ushort8v*)(T1 + (size_t)srcr * 256 + sl * 8);
#pragma unroll
    for (int i = 0; i < 8; ++i) s[i] += bf2f(v[i]);
  }
#pragma unroll
  for (int i = 0; i < 8; ++i) s[i] += __shfl_xor(s[i], 32);
  int dg = end - beg;
  float inv = 1.0f / (float)(dg > 0 ? dg : 1);
  const float4* t2p = (const float4*)(T2 + (size_t)n * 256 + sl * 8);
  float4 ta = t2p[0], tb = t2p[1];
  float h[8];
  h[0] = fmaxf(s[0] * inv + ta.x, 0.f);
  h[1] = fmaxf(s[1] * inv + ta.y, 0.f);
  h[2] = fmaxf(s[2] * inv + ta.z, 0.f);
  h[3] = fmaxf(s[3] * inv + ta.w, 0.f);
  h[4] = fmaxf(s[4] * inv + tb.x, 0.f);
  h[5] = fmaxf(s[5] * inv + tb.y, 0.f);
  h[6] = fmaxf(s[6] * inv + tb.z, 0.f);
  h[7] = fmaxf(s[7] * inv + tb.w, 0.f);
  if (half == 0) {
    ushort8v hh;
#pragma unroll
    for (int i = 0; i < 8; ++i) hh[i] = f2bf(h[i]);
    *(ushort8v*)(Hh + (size_t)n * 256 + sl * 8) = hh;
  } else {
    ushort8v hl;
#pragma unroll
    for (int i = 0; i < 8; ++i) {
      unsigned short hi = f2bf(h[i]);
      hl[i] = f2bf(h[i] - bf2f(hi));
    }
    *(ushort8v*)(Hl + (size_t)n * 256 + sl * 8) = hl;
  }
}

// ---------------- final: out = softmax(H[M,256] @ Wm2[8,256]^T + bm2) ----------------

__global__ __launch_bounds__(256) void k_final(const float* __restrict__ H,
                                               const float* __restrict__ Wm2,
                                               const float* __restrict__ bm2,
                                               float* __restrict__ out, int M) {
  int node = blockIdx.x * 4 + (threadIdx.x >> 6);
  int lane = threadIdx.x & 63;
  if (node >= M) return;
  int o = lane >> 3;
  int r = lane & 7;
  const float* h = H + (size_t)node * D;
  const float* w = Wm2 + (size_t)o * D;
  float p = 0.f;
  for (int k = r; k < D; k += 8) p += h[k] * w[k];
  p += __shfl_xor(p, 1);
  p += __shfl_xor(p, 2);
  p += __shfl_xor(p, 4);
  float logit = p + bm2[o];
  float m = logit;
  m = fmaxf(m, __shfl_xor(m, 8));
  m = fmaxf(m, __shfl_xor(m, 16));
  m = fmaxf(m, __shfl_xor(m, 32));
  float e = expf(logit - m);
  float s = e;
  s += __shfl_xor(s, 8);
  s += __shfl_xor(s, 16);
  s += __shfl_xor(s, 32);
  if (r == 0) out[(size_t)node * 8 + o] = e / s;
}

// ---------------- launch ----------------

extern "C" void kernel_launch(void* const* d_in, const int* in_sizes, int n_in,
                              void* d_out, int out_size, void* d_ws, size_t ws_size,
                              hipStream_t stream) {
  const float* x   = (const float*)d_in[0];
  const int*   ei  = (const int*)d_in[1];
  const float* W1l = (const float*)d_in[2];
  const float* b1  = (const float*)d_in[3];
  const float* W1r = (const float*)d_in[4];
  const float* W2l = (const float*)d_in[5];
  const float* b2  = (const float*)d_in[6];
  const float* W2r = (const float*)d_in[7];
  const float* Wm1 = (const float*)d_in[8];
  const float* bm1 = (const float*)d_in[9];
  const float* Wm2 = (const float*)d_in[10];
  const float* bm2 = (const float*)d_in[11];
  float* out = (float*)d_out;

  int M = in_sizes[0] / D;   // 50000
  int E = in_sizes[1] / 2;   // 800000
  const int* src = ei;
  const int* dst = ei + E;

  char* p = (char*)d_ws;
  auto alloc = [&](size_t bytes) {
    char* q = p;
    p += (bytes + 255) & ~(size_t)255;
    return q;
  };
  unsigned short* bh0  = (unsigned short*)alloc((size_t)M * 256 * 2);  // x/h split hi
  unsigned short* bh1  = (unsigned short*)alloc((size_t)M * 256 * 2);  // x/h split lo
  unsigned short* T1bf = (unsigned short*)alloc((size_t)M * 256 * 2);  // neighbor-path (bf16)
  float*          T2f  = (float*)alloc((size_t)M * 256 * 4);           // root-path / mlp out (f32)
  unsigned short* Wc1h = (unsigned short*)alloc(512 * 256 * 2);
  unsigned short* Wc1l = (unsigned short*)alloc(512 * 256 * 2);
  unsigned short* Wc2h = (unsigned short*)alloc(512 * 256 * 2);
  unsigned short* Wc2l = (unsigned short*)alloc(512 * 256 * 2);
  unsigned short* Wm1h = (unsigned short*)alloc(256 * 256 * 2);
  unsigned short* Wm1l = (unsigned short*)alloc(256 * 256 * 2);
  int* deg     = (int*)alloc((size_t)M * 4);
  int* row_ptr = (int*)alloc((size_t)(M + 1) * 4);
  int* cursor  = (int*)alloc((size_t)M * 4);
  int* col     = (int*)alloc((size_t)E * 4);
  int* bsum    = (int*)alloc(64 * 4);
  int* boff    = (int*)alloc(64 * 4);

  int nb = (M + 1023) / 1024;  // 49

  // CSR build
  hipMemsetAsync(deg, 0, (size_t)M * sizeof(int), stream);
  k_deg<<<dim3((E + 255) / 256), dim3(256), 0, stream>>>(dst, deg, E);
  k_bsum<<<dim3(nb), dim3(256), 0, stream>>>(deg, bsum, M);
  k_scanb<<<dim3(1), dim3(64), 0, stream>>>(bsum, boff, row_ptr, nb, M);
  k_apply<<<dim3(nb), dim3(256), 0, stream>>>(deg, boff, row_ptr, cursor, M);
  k_fill<<<dim3((E + 255) / 256), dim3(256), 0, stream>>>(src, dst, cursor, col, E);

  // split conversions
  int nx4 = M * 256 / 4;
  k_split<<<dim3((nx4 + 255) / 256), dim3(256), 0, stream>>>(x, bh0, bh1, nx4);
  k_splitw<<<dim3(64, 5), dim3(256), 0, stream>>>(
      W1l, W1r, W2l, W2r, Wm1,
      Wc1h, Wc1l, Wc1h + 65536, Wc1l + 65536,
      Wc2h, Wc2l, Wc2h + 65536, Wc2l + 65536,
      Wm1h, Wm1l);

  dim3 blk(256);
  int nwg4 = ((M + 127) / 128) * 4;  // 1564
  int nwg2 = ((M + 127) / 128) * 2;  // 782
  int aggGrid = (M + 3) / 4;

  // Layer 1: [T1 | T2] = x @ [W1l;W1r]^T ; T2 += b1 ; h1 = relu(mean(T1)+T2) -> split into bh0/bh1
  k_gemm_mfma<<<dim3(nwg4), blk, 0, stream>>>(bh0, bh1, Wc1h, Wc1l, T1bf, T2f, b1, M, 256, 256, 0, 2);
  k_agg2<<<dim3(aggGrid), blk, 0, stream>>>(T1bf, T2f, bh0, bh1, row_ptr, col, M);
  // Layer 2
  k_gemm_mfma<<<dim3(nwg4), blk, 0, stream>>>(bh0, bh1, Wc2h, Wc2l, T1bf, T2f, b2, M, 256, 256, 0, 2);
  k_agg2<<<dim3(aggGrid), blk, 0, stream>>>(T1bf, T2f, bh0, bh1, row_ptr, col, M);
  // MLP layer 1: h3 = relu(h2 @ Wm1^T + bm1) -> T2f
  k_gemm_mfma<<<dim3(nwg2), blk, 0, stream>>>(bh0, bh1, Wm1h, Wm1l, nullptr, T2f, bm1, M, 0, 256, 1, 1);
  // logits + softmax
  k_final<<<dim3((M + 3) / 4), blk, 0, stream>>>(T2f, Wm2, bm2, out, M);
}

// Round 7
// 570.963 us; speedup vs baseline: 1.1999x; 1.0166x over previous
//
#include <hip/hip_runtime.h>
#include <hip/hip_bf16.h>
#include <cstdint>
#include <cstddef>

#define D 256

typedef __attribute__((ext_vector_type(8))) short bf16x8;
typedef __attribute__((ext_vector_type(4))) float f32x4;
typedef __attribute__((ext_vector_type(4))) unsigned short ushort4v;
typedef __attribute__((ext_vector_type(8))) unsigned short ushort8v;

__device__ __forceinline__ unsigned short f2bf(float f) {  // RNE
  union { float f; unsigned int u; } v; v.f = f;
  unsigned int u = v.u;
  u += ((u >> 16) & 1u) + 0x7fffu;
  return (unsigned short)(u >> 16);
}
__device__ __forceinline__ float bf2f(unsigned short s) {
  union { unsigned int u; float f; } v; v.u = ((unsigned int)s) << 16;
  return v.f;
}

#define GLL16(g, l) __builtin_amdgcn_global_load_lds( \
    (const __attribute__((address_space(1))) void*)(g), \
    (__attribute__((address_space(3))) void*)(l), 16, 0, 0)

// ---------------- CSR build ----------------

__global__ __launch_bounds__(256) void k_deg(const int* __restrict__ dst,
                                             int* __restrict__ deg, int E) {
  int e = blockIdx.x * 256 + threadIdx.x;
  if (e < E) atomicAdd(&deg[dst[e]], 1);
}

__global__ __launch_bounds__(256) void k_bsum(const int* __restrict__ deg,
                                              int* __restrict__ bsum, int M) {
  __shared__ int sm[256];
  int tid = threadIdx.x;
  int base = blockIdx.x * 1024 + tid * 4;
  int s = 0;
#pragma unroll
  for (int i = 0; i < 4; ++i) s += (base + i < M) ? deg[base + i] : 0;
  sm[tid] = s;
  __syncthreads();
  for (int off = 128; off > 0; off >>= 1) {
    if (tid < off) sm[tid] += sm[tid + off];
    __syncthreads();
  }
  if (tid == 0) bsum[blockIdx.x] = sm[0];
}

__global__ __launch_bounds__(64) void k_scanb(const int* __restrict__ bsum,
                                              int* __restrict__ boff,
                                              int* __restrict__ row_ptr,
                                              int nb, int M) {
  int l = threadIdx.x;
  int orig = (l < nb) ? bsum[l] : 0;
  int v = orig;
  for (int off = 1; off < 64; off <<= 1) {
    int t = __shfl_up(v, off);
    if (l >= off) v += t;
  }
  if (l < nb) boff[l] = v - orig;
  if (l == nb - 1) row_ptr[M] = v;
}

__global__ __launch_bounds__(256) void k_apply(const int* __restrict__ deg,
                                               const int* __restrict__ boff,
                                               int* __restrict__ row_ptr,
                                               int* __restrict__ cursor, int M) {
  __shared__ int sm[256];
  int tid = threadIdx.x;
  int base = blockIdx.x * 1024 + tid * 4;
  int d[4], p[4];
#pragma unroll
  for (int i = 0; i < 4; ++i) d[i] = (base + i < M) ? deg[base + i] : 0;
  p[0] = 0; p[1] = d[0]; p[2] = d[0] + d[1]; p[3] = d[0] + d[1] + d[2];
  int s = p[3] + d[3];
  sm[tid] = s;
  __syncthreads();
  for (int off = 1; off < 256; off <<= 1) {
    int t = (tid >= off) ? sm[tid - off] : 0;
    __syncthreads();
    sm[tid] += t;
    __syncthreads();
  }
  int excl = sm[tid] - s + boff[blockIdx.x];
#pragma unroll
  for (int i = 0; i < 4; ++i) {
    if (base + i < M) {
      row_ptr[base + i] = excl + p[i];
      cursor[base + i] = excl + p[i];
    }
  }
}

__global__ __launch_bounds__(256) void k_fill(const int* __restrict__ src,
                                              const int* __restrict__ dst,
                                              int* __restrict__ cursor,
                                              int* __restrict__ col, int E) {
  int e = blockIdx.x * 256 + threadIdx.x;
  if (e < E) {
    int p = atomicAdd(&cursor[dst[e]], 1);
    col[p] = src[e];
  }
}

// ---------------- fp32 -> split bf16 (hi, lo) ----------------

__global__ __launch_bounds__(256) void k_split(const float* __restrict__ in,
                                               unsigned short* __restrict__ oh,
                                               unsigned short* __restrict__ ol,
                                               int n4) {
  int i = blockIdx.x * 256 + threadIdx.x;
  if (i >= n4) return;
  float4 v = ((const float4*)in)[i];
  float a[4] = {v.x, v.y, v.z, v.w};
  ushort4v h, l;
#pragma unroll
  for (int j = 0; j < 4; ++j) {
    h[j] = f2bf(a[j]);
    l[j] = f2bf(a[j] - bf2f(h[j]));
  }
  ((ushort4v*)oh)[i] = h;
  ((ushort4v*)ol)[i] = l;
}

// all 5 weight matrices (each 256x256) in one dispatch; blockIdx.y selects.
__global__ __launch_bounds__(256) void k_splitw(
    const float* __restrict__ s0, const float* __restrict__ s1,
    const float* __restrict__ s2, const float* __restrict__ s3,
    const float* __restrict__ s4,
    unsigned short* __restrict__ h0, unsigned short* __restrict__ l0,
    unsigned short* __restrict__ h1, unsigned short* __restrict__ l1,
    unsigned short* __restrict__ h2, unsigned short* __restrict__ l2,
    unsigned short* __restrict__ h3, unsigned short* __restrict__ l3,
    unsigned short* __restrict__ h4, unsigned short* __restrict__ l4) {
  const float* s; unsigned short* oh; unsigned short* ol;
  switch (blockIdx.y) {
    case 0: s = s0; oh = h0; ol = l0; break;
    case 1: s = s1; oh = h1; ol = l1; break;
    case 2: s = s2; oh = h2; ol = l2; break;
    case 3: s = s3; oh = h3; ol = l3; break;
    default: s = s4; oh = h4; ol = l4; break;
  }
  int i = blockIdx.x * 256 + threadIdx.x;  // 16384 float4s per matrix
  float4 v = ((const float4*)s)[i];
  float a[4] = {v.x, v.y, v.z, v.w};
  ushort4v h, l;
#pragma unroll
  for (int j = 0; j < 4; ++j) {
    h[j] = f2bf(a[j]);
    l[j] = f2bf(a[j] - bf2f(h[j]));
  }
  ((ushort4v*)oh)[i] = h;
  ((ushort4v*)ol)[i] = l;
}

// ---------------- split-bf16 MFMA GEMM ----------------
// C[M, NBF+NF] = (Ah+Al)[M,256] @ (Wh+Wl)[NBF+NF,256]^T  (3-term split product)
// 1-D grid, bijective XCD-chunk swizzle with bx fastest (A-tile L2 reuse).
// Double-buffered LDS (2 x 32 KB) with raw s_barrier + counted vmcnt(8):
// next tile's global_load_lds fly for a FULL iteration before being consumed;
// no vmcnt(0) drain inside the main loop.

__global__ __launch_bounds__(256) void k_gemm_mfma(
    const unsigned short* __restrict__ Ah, const unsigned short* __restrict__ Al,
    const unsigned short* __restrict__ Wh, const unsigned short* __restrict__ Wl,
    unsigned short* __restrict__ outBF, float* __restrict__ outF32,
    const float* __restrict__ bias, int M, int NBF, int NF, int relu,
    int nbxshift) {
  __shared__ char lds[65536];  // 2 buffers x (Ah 8K | Al 8K | Wh 8K | Wl 8K)

  const int tid = threadIdx.x;
  const int wave = tid >> 6;
  const int lane = tid & 63;

  // bijective XCD-chunk swizzle: consecutive logical ids run on one XCD.
  int nwg = gridDim.x;
  int id = blockIdx.x;
  int q = nwg >> 3, r = nwg & 7;
  int xcd = id & 7, j = id >> 3;
  int w = ((xcd < r) ? xcd * (q + 1) : r * (q + 1) + (xcd - r) * q) + j;
  const int by = w >> nbxshift;
  const int bx = w & ((1 << nbxshift) - 1);
  const int n0 = bx * 128;

  // staging: linear LDS dest (base + lane*16), global source pre-permuted
  // so that a read at logical k-slot g uses physical slot g ^ ((row>>1)&3).
  int aoff[2], woff[2], ldso[2];
#pragma unroll
  for (int rr = 0; rr < 2; ++rr) {
    int o = rr * 4096 + wave * 1024 + lane * 16;  // byte offset in tile
    int row = o >> 6;                             // 64 B per row (32 bf16)
    int sp = (o >> 4) & 3;                        // physical 16B slot
    int sl = sp ^ ((row >> 1) & 3);               // logical k-slot stored here
    int arow = by * 128 + row; if (arow > M - 1) arow = M - 1;
    aoff[rr] = arow * 256 + sl * 8;               // elements
    woff[rr] = (n0 + row) * 256 + sl * 8;
    ldso[rr] = rr * 4096 + wave * 1024;           // wave-uniform LDS base
  }

  const int rbase = (wave >> 1) * 64;
  const int cbase = (wave & 1) * 64;
  const int fr = lane & 15;
  const int g = lane >> 4;

  int a_addr[4], w_addr[4];
#pragma unroll
  for (int m = 0; m < 4; ++m) {
    int row = rbase + m * 16 + fr;
    a_addr[m] = row * 64 + ((g ^ ((row >> 1) & 3)) * 16);
  }
#pragma unroll
  for (int n = 0; n < 4; ++n) {
    int row = cbase + n * 16 + fr;
    w_addr[n] = row * 64 + ((g ^ ((row >> 1) & 3)) * 16);
  }

  f32x4 acc[4][4] = {};

  // prologue: stage step 0 into buffer 0
#pragma unroll
  for (int rr = 0; rr < 2; ++rr) {
    GLL16(Ah + aoff[rr], lds + 0     + ldso[rr]);
    GLL16(Al + aoff[rr], lds + 8192  + ldso[rr]);
    GLL16(Wh + woff[rr], lds + 16384 + ldso[rr]);
    GLL16(Wl + woff[rr], lds + 24576 + ldso[rr]);
  }

  for (int t = 0; t < 8; ++t) {
    const int cb = (t & 1) * 32768;        // current buffer
    if (t < 7) {
      const int nb = ((t + 1) & 1) * 32768;
      const int ko = (t + 1) * 32;
#pragma unroll
      for (int rr = 0; rr < 2; ++rr) {
        GLL16(Ah + aoff[rr] + ko, lds + nb + 0     + ldso[rr]);
        GLL16(Al + aoff[rr] + ko, lds + nb + 8192  + ldso[rr]);
        GLL16(Wh + woff[rr] + ko, lds + nb + 16384 + ldso[rr]);
        GLL16(Wl + woff[rr] + ko, lds + nb + 24576 + ldso[rr]);
      }
      asm volatile("s_waitcnt vmcnt(8)" ::: "memory");  // oldest 8 (cur buf) done
    } else {
      asm volatile("s_waitcnt vmcnt(0)" ::: "memory");
    }
    __builtin_amdgcn_s_barrier();          // all waves' cur-buf loads done

    bf16x8 ah[4], al[4], wh[4], wl[4];
#pragma unroll
    for (int m = 0; m < 4; ++m) {
      ah[m] = *(const bf16x8*)(lds + cb + 0    + a_addr[m]);
      al[m] = *(const bf16x8*)(lds + cb + 8192 + a_addr[m]);
    }
#pragma unroll
    for (int n = 0; n < 4; ++n) {
      wh[n] = *(const bf16x8*)(lds + cb + 16384 + w_addr[n]);
      wl[n] = *(const bf16x8*)(lds + cb + 24576 + w_addr[n]);
    }
#pragma unroll
    for (int m = 0; m < 4; ++m)
#pragma unroll
      for (int n = 0; n < 4; ++n) {
        acc[m][n] = __builtin_amdgcn_mfma_f32_16x16x32_bf16(ah[m], wh[n], acc[m][n], 0, 0, 0);
        acc[m][n] = __builtin_amdgcn_mfma_f32_16x16x32_bf16(ah[m], wl[n], acc[m][n], 0, 0, 0);
        acc[m][n] = __builtin_amdgcn_mfma_f32_16x16x32_bf16(al[m], wh[n], acc[m][n], 0, 0, 0);
      }
    __builtin_amdgcn_s_barrier();          // all waves done reading cur buf
  }

  // epilogue: C/D layout col=lane&15, row=(lane>>4)*4+reg — direct stores
#pragma unroll
  for (int n = 0; n < 4; ++n) {
    int col = n0 + cbase + n * 16 + fr;
    bool isbf = col < NBF;
    int fcol = col - NBF;
    float bv = (!isbf && bias) ? bias[fcol] : 0.f;
#pragma unroll
    for (int m = 0; m < 4; ++m) {
      f32x4 a = acc[m][n];
#pragma unroll
      for (int rr = 0; rr < 4; ++rr) {
        int row = by * 128 + rbase + m * 16 + g * 4 + rr;
        if (row < M) {
          if (isbf) {
            outBF[(size_t)row * NBF + col] = f2bf(a[rr]);
          } else {
            float v = a[rr] + bv;
            if (relu) v = fmaxf(v, 0.f);
            outF32[(size_t)row * NF + fcol] = v;
          }
        }
      }
    }
  }
}

// ---------------- aggregation ----------------
// one wave per node; lanes split in 2 halves, 2-deep unroll -> 4 row-gathers
// in flight per wave. Combine halves via shfl_xor(32).

__global__ __launch_bounds__(256) void k_agg2(const unsigned short* __restrict__ T1,
                                              const float* __restrict__ T2,
                                              unsigned short* __restrict__ Hh,
                                              unsigned short* __restrict__ Hl,
                                              const int* __restrict__ row_ptr,
                                              const int* __restrict__ col, int M) {
  int wave = threadIdx.x >> 6, lane = threadIdx.x & 63;
  int n = blockIdx.x * 4 + wave;
  if (n >= M) return;
  int beg = row_ptr[n], end = row_ptr[n + 1];
  int half = lane >> 5, sl = lane & 31;
  float s[8] = {0.f, 0.f, 0.f, 0.f, 0.f, 0.f, 0.f, 0.f};
  int j = beg + half;
  for (; j + 2 < end; j += 4) {
    int i0 = col[j];
    int i1 = col[j + 2];
    ushort8v v0 = *(const ushort8v*)(T1 + (size_t)i0 * 256 + sl * 8);
    ushort8v v1 = *(const ushort8v*)(T1 + (size_t)i1 * 256 + sl * 8);
#pragma unroll
    for (int i = 0; i < 8; ++i) s[i] += bf2f(v0[i]) + bf2f(v1[i]);
  }
  for (; j < end; j += 2) {
    int i0 = col[j];
    ushort8v v0 = *(const ushort8v*)(T1 + (size_t)i0 * 256 + sl * 8);
#pragma unroll
    for (int i = 0; i < 8; ++i) s[i] += bf2f(v0[i]);
  }
#pragma unroll
  for (int i = 0; i < 8; ++i) s[i] += __shfl_xor(s[i], 32);
  int dg = end - beg;
  float inv = 1.0f / (float)(dg > 0 ? dg : 1);
  const float4* t2p = (const float4*)(T2 + (size_t)n * 256 + sl * 8);
  float4 ta = t2p[0], tb = t2p[1];
  float h[8];
  h[0] = fmaxf(s[0] * inv + ta.x, 0.f);
  h[1] = fmaxf(s[1] * inv + ta.y, 0.f);
  h[2] = fmaxf(s[2] * inv + ta.z, 0.f);
  h[3] = fmaxf(s[3] * inv + ta.w, 0.f);
  h[4] = fmaxf(s[4] * inv + tb.x, 0.f);
  h[5] = fmaxf(s[5] * inv + tb.y, 0.f);
  h[6] = fmaxf(s[6] * inv + tb.z, 0.f);
  h[7] = fmaxf(s[7] * inv + tb.w, 0.f);
  if (half == 0) {
    ushort8v hh;
#pragma unroll
    for (int i = 0; i < 8; ++i) hh[i] = f2bf(h[i]);
    *(ushort8v*)(Hh + (size_t)n * 256 + sl * 8) = hh;
  } else {
    ushort8v hl;
#pragma unroll
    for (int i = 0; i < 8; ++i) {
      unsigned short hi = f2bf(h[i]);
      hl[i] = f2bf(h[i] - bf2f(hi));
    }
    *(ushort8v*)(Hl + (size_t)n * 256 + sl * 8) = hl;
  }
}

// ---------------- final: out = softmax(H[M,256] @ Wm2[8,256]^T + bm2) ----------------

__global__ __launch_bounds__(256) void k_final(const float* __restrict__ H,
                                               const float* __restrict__ Wm2,
                                               const float* __restrict__ bm2,
                                               float* __restrict__ out, int M) {
  int node = blockIdx.x * 4 + (threadIdx.x >> 6);
  int lane = threadIdx.x & 63;
  if (node >= M) return;
  int o = lane >> 3;
  int r = lane & 7;
  const float* h = H + (size_t)node * D;
  const float* w = Wm2 + (size_t)o * D;
  float p = 0.f;
  for (int k = r; k < D; k += 8) p += h[k] * w[k];
  p += __shfl_xor(p, 1);
  p += __shfl_xor(p, 2);
  p += __shfl_xor(p, 4);
  float logit = p + bm2[o];
  float m = logit;
  m = fmaxf(m, __shfl_xor(m, 8));
  m = fmaxf(m, __shfl_xor(m, 16));
  m = fmaxf(m, __shfl_xor(m, 32));
  float e = expf(logit - m);
  float s = e;
  s += __shfl_xor(s, 8);
  s += __shfl_xor(s, 16);
  s += __shfl_xor(s, 32);
  if (r == 0) out[(size_t)node * 8 + o] = e / s;
}

// ---------------- launch ----------------

extern "C" void kernel_launch(void* const* d_in, const int* in_sizes, int n_in,
                              void* d_out, int out_size, void* d_ws, size_t ws_size,
                              hipStream_t stream) {
  const float* x   = (const float*)d_in[0];
  const int*   ei  = (const int*)d_in[1];
  const float* W1l = (const float*)d_in[2];
  const float* b1  = (const float*)d_in[3];
  const float* W1r = (const float*)d_in[4];
  const float* W2l = (const float*)d_in[5];
  const float* b2  = (const float*)d_in[6];
  const float* W2r = (const float*)d_in[7];
  const float* Wm1 = (const float*)d_in[8];
  const float* bm1 = (const float*)d_in[9];
  const float* Wm2 = (const float*)d_in[10];
  const float* bm2 = (const float*)d_in[11];
  float* out = (float*)d_out;

  int M = in_sizes[0] / D;   // 50000
  int E = in_sizes[1] / 2;   // 800000
  const int* src = ei;
  const int* dst = ei + E;

  char* p = (char*)d_ws;
  auto alloc = [&](size_t bytes) {
    char* q = p;
    p += (bytes + 255) & ~(size_t)255;
    return q;
  };
  unsigned short* bh0  = (unsigned short*)alloc((size_t)M * 256 * 2);  // x/h split hi
  unsigned short* bh1  = (unsigned short*)alloc((size_t)M * 256 * 2);  // x/h split lo
  unsigned short* T1bf = (unsigned short*)alloc((size_t)M * 256 * 2);  // neighbor-path (bf16)
  float*          T2f  = (float*)alloc((size_t)M * 256 * 4);           // root-path / mlp out (f32)
  unsigned short* Wc1h = (unsigned short*)alloc(512 * 256 * 2);
  unsigned short* Wc1l = (unsigned short*)alloc(512 * 256 * 2);
  unsigned short* Wc2h = (unsigned short*)alloc(512 * 256 * 2);
  unsigned short* Wc2l = (unsigned short*)alloc(512 * 256 * 2);
  unsigned short* Wm1h = (unsigned short*)alloc(256 * 256 * 2);
  unsigned short* Wm1l = (unsigned short*)alloc(256 * 256 * 2);
  int* deg     = (int*)alloc((size_t)M * 4);
  int* row_ptr = (int*)alloc((size_t)(M + 1) * 4);
  int* cursor  = (int*)alloc((size_t)M * 4);
  int* col     = (int*)alloc((size_t)E * 4);
  int* bsum    = (int*)alloc(64 * 4);
  int* boff    = (int*)alloc(64 * 4);

  int nb = (M + 1023) / 1024;  // 49

  // CSR build
  hipMemsetAsync(deg, 0, (size_t)M * sizeof(int), stream);
  k_deg<<<dim3((E + 255) / 256), dim3(256), 0, stream>>>(dst, deg, E);
  k_bsum<<<dim3(nb), dim3(256), 0, stream>>>(deg, bsum, M);
  k_scanb<<<dim3(1), dim3(64), 0, stream>>>(bsum, boff, row_ptr, nb, M);
  k_apply<<<dim3(nb), dim3(256), 0, stream>>>(deg, boff, row_ptr, cursor, M);
  k_fill<<<dim3((E + 255) / 256), dim3(256), 0, stream>>>(src, dst, cursor, col, E);

  // split conversions
  int nx4 = M * 256 / 4;
  k_split<<<dim3((nx4 + 255) / 256), dim3(256), 0, stream>>>(x, bh0, bh1, nx4);
  k_splitw<<<dim3(64, 5), dim3(256), 0, stream>>>(
      W1l, W1r, W2l, W2r, Wm1,
      Wc1h, Wc1l, Wc1h + 65536, Wc1l + 65536,
      Wc2h, Wc2l, Wc2h + 65536, Wc2l + 65536,
      Wm1h, Wm1l);

  dim3 blk(256);
  int nwg4 = ((M + 127) / 128) * 4;  // 1564
  int nwg2 = ((M + 127) / 128) * 2;  // 782
  int aggGrid = (M + 3) / 4;

  // Layer 1: [T1 | T2] = x @ [W1l;W1r]^T ; T2 += b1 ; h1 = relu(mean(T1)+T2) -> split into bh0/bh1
  k_gemm_mfma<<<dim3(nwg4), blk, 0, stream>>>(bh0, bh1, Wc1h, Wc1l, T1bf, T2f, b1, M, 256, 256, 0, 2);
  k_agg2<<<dim3(aggGrid), blk, 0, stream>>>(T1bf, T2f, bh0, bh1, row_ptr, col, M);
  // Layer 2
  k_gemm_mfma<<<dim3(nwg4), blk, 0, stream>>>(bh0, bh1, Wc2h, Wc2l, T1bf, T2f, b2, M, 256, 256, 0, 2);
  k_agg2<<<dim3(aggGrid), blk, 0, stream>>>(T1bf, T2f, bh0, bh1, row_ptr, col, M);
  // MLP layer 1: h3 = relu(h2 @ Wm1^T + bm1) -> T2f
  k_gemm_mfma<<<dim3(nwg2), blk, 0, stream>>>(bh0, bh1, Wm1h, Wm1l, nullptr, T2f, bm1, M, 0, 256, 1, 1);
  // logits + softmax
  k_final<<<dim3((M + 3) / 4), blk, 0, stream>>>(T2f, Wm2, bm2, out, M);
}